// Round 2
// baseline (408.058 us; speedup 1.0000x reference)
//
#include <hip/hip_runtime.h>

#define NBOX   2048
#define MAXDET 100
#define NIMG   8
#define BLK    1024

__global__ __launch_bounds__(BLK) void region_extractor_kernel(
    const float* __restrict__ boxes,   // [NIMG, NBOX, 4] xyxy
    const float* __restrict__ scores,  // [NIMG, NBOX]
    float* __restrict__ out)           // [NIMG*MAXDET*5] regions ++ [NIMG*MAXDET] mask
{
    __shared__ unsigned long long keys[NBOX];                 // 16 KB
    __shared__ float sx1[NBOX], sy1[NBOX], sx2[NBOX], sy2[NBOX]; // 32 KB
    __shared__ int flags[NBOX];                               // 8 KB (1 = suppressed/invalid)

    const int tid = threadIdx.x;
    const int b   = blockIdx.x;
    const float* bb = boxes  + (size_t)b * NBOX * 4;
    const float* ss = scores + (size_t)b * NBOX;

    // ---- Phase A: validity + composite sort key -------------------------
    // key = (score_bits << 32) | ~idx  -> descending sort == (score desc, idx asc)
    // invalid -> score_bits = 0 (matches -inf: sorts last; order among them irrelevant)
    for (int i = tid; i < NBOX; i += BLK) {
        float x1 = bb[i * 4 + 0], y1 = bb[i * 4 + 1];
        float x2 = bb[i * 4 + 2], y2 = bb[i * 4 + 3];
        float s  = ss[i];
        bool valid = ((x2 - x1) >= 25.0f) && ((y2 - y1) >= 25.0f) && (s >= 0.001f);
        unsigned int sk = valid ? __float_as_uint(s) : 0u;   // scores in [0,1): bits order-preserving
        keys[i] = ((unsigned long long)sk << 32) | (unsigned int)(~i);
    }
    __syncthreads();

    // ---- Phase B: bitonic sort, descending ------------------------------
    for (int k = 2; k <= NBOX; k <<= 1) {
        for (int j = k >> 1; j > 0; j >>= 1) {
            for (int t = tid; t < NBOX; t += BLK) {
                int ixj = t ^ j;
                if (ixj > t) {
                    unsigned long long a = keys[t], c = keys[ixj];
                    bool desc = ((t & k) == 0);
                    bool sw = desc ? (a < c) : (a > c);
                    if (sw) { keys[t] = c; keys[ixj] = a; }
                }
            }
            __syncthreads();
        }
    }

    // ---- Phase C: stage sorted boxes + flags ----------------------------
    for (int i = tid; i < NBOX; i += BLK) {
        unsigned long long key = keys[i];
        unsigned int idx = ~(unsigned int)key;               // recover original index
        const float* bp = bb + (size_t)idx * 4;
        sx1[i] = bp[0]; sy1[i] = bp[1]; sx2[i] = bp[2]; sy2[i] = bp[3];
        flags[i] = ((unsigned int)(key >> 32) == 0u) ? 1 : 0;
    }
    __syncthreads();

    // ---- Phase D: single-wave greedy NMS (wave 0 only, no barriers) -----
    if (tid >= 64) return;
    const int lane = tid;
    float* regions = out;
    float* maskv   = out + (size_t)NIMG * MAXDET * 5;

    int p = 0, nkept = 0;
    while (p < NBOX && nkept < MAXDET) {
        // ballot-scan for next unsuppressed candidate
        int m = p + lane;
        int f = (m < NBOX) ? flags[m] : 1;
        unsigned long long bal = __ballot(f == 0);
        if (bal == 0ULL) { p += 64; continue; }
        int lead = p + (int)__builtin_ctzll(bal);

        // broadcast leader box (uniform LDS address -> broadcast read)
        float lx1 = sx1[lead], ly1 = sy1[lead], lx2 = sx2[lead], ly2 = sy2[lead];
        float larea = (lx2 - lx1) * (ly2 - ly1);

        if (lane == 0) {
            float* r = regions + ((size_t)b * MAXDET + nkept) * 5;
            r[0] = (float)b; r[1] = lx1; r[2] = ly1; r[3] = lx2; r[4] = ly2;
            maskv[b * MAXDET + nkept] = 1.0f;
        }
        nkept++;

        // parallel suppression sweep vs leader (mirror reference f32 op order)
        for (int q = lead + 1 + lane; q < NBOX; q += 64) {
            float x1 = sx1[q], y1 = sy1[q], x2 = sx2[q], y2 = sy2[q];
            float iw = fmaxf(fminf(lx2, x2) - fmaxf(lx1, x1), 0.0f);
            float ih = fmaxf(fminf(ly2, y2) - fmaxf(ly1, y1), 0.0f);
            float inter = iw * ih;
            float area  = (x2 - x1) * (y2 - y1);
            float iou   = inter / ((larea + area) - inter);
            if (iou > 0.3f) flags[q] = 1;   // never unset; invalid already 1
        }
        p = lead + 1;
    }

    // ---- Phase E: fill padding rows (d_out is poisoned every launch) ----
    for (int k2 = nkept + lane; k2 < MAXDET; k2 += 64) {
        float* r = regions + ((size_t)b * MAXDET + k2) * 5;
        r[0] = (float)b; r[1] = 0.0f; r[2] = 0.0f; r[3] = 0.0f; r[4] = 0.0f;
        maskv[b * MAXDET + k2] = 0.0f;
    }
}

extern "C" void kernel_launch(void* const* d_in, const int* in_sizes, int n_in,
                              void* d_out, int out_size, void* d_ws, size_t ws_size,
                              hipStream_t stream) {
    const float* boxes  = (const float*)d_in[0];  // [8,2048,4] f32
    const float* scores = (const float*)d_in[1];  // [8,2048]   f32
    float* out = (float*)d_out;                   // 4800 f32: regions(4000) ++ mask(800)
    region_extractor_kernel<<<NIMG, BLK, 0, stream>>>(boxes, scores, out);
}

// Round 3
// 230.669 us; speedup vs baseline: 1.7690x; 1.7690x over previous
//
#include <hip/hip_runtime.h>

#define NBOX   2048
#define MAXDET 100
#define NIMG   8
#define BLK    512
// midpoint(0.3f, nextafterf(0.3f, +inf)) in double:
// RN_f32(inter/denom) > 0.3f  <=>  inter > IOU_MID * denom  (exact: 25b x 24b product fits f64)
#define IOU_MID 0x1.333335p-2

__global__ __launch_bounds__(BLK) void region_extractor_kernel(
    const float* __restrict__ boxes,   // [NIMG, NBOX, 4] xyxy
    const float* __restrict__ scores,  // [NIMG, NBOX]
    float* __restrict__ out)           // [NIMG*MAXDET*5] regions ++ [NIMG*MAXDET] mask
{
    __shared__ unsigned long long keys[NBOX];   // 16 KB
    __shared__ float4 sbox[NBOX];               // 32 KB, XOR-swizzled: phys = i ^ ((i>>5)&7)
    __shared__ unsigned int aliveW[NBOX / 32];  // 64 words: bit (i&31) of word (i>>5) = valid

    const int tid = threadIdx.x;
    const int b   = blockIdx.x;
    const float4* bb4 = (const float4*)(boxes + (size_t)b * NBOX * 4);
    const float*  ss  = scores + (size_t)b * NBOX;

    // ---- Phase A: validity + composite sort key -------------------------
    // key = (score_bits << 32) | ~idx : descending sort == (score desc, idx asc);
    // invalid -> hi = 0 (== -inf: sorts last)
    for (int i = tid; i < NBOX; i += BLK) {
        float4 v = bb4[i];
        float  s = ss[i];
        bool valid = ((v.z - v.x) >= 25.0f) && ((v.w - v.y) >= 25.0f) && (s >= 0.001f);
        unsigned int sk = valid ? __float_as_uint(s) : 0u;  // scores in [0,1): bits monotone
        keys[i] = ((unsigned long long)sk << 32) | (unsigned int)(~i);
    }
    __syncthreads();

    // ---- Phase B: bitonic sort, descending ------------------------------
    for (int k = 2; k <= NBOX; k <<= 1) {
        for (int j = k >> 1; j > 0; j >>= 1) {
            for (int t = tid; t < NBOX; t += BLK) {
                int ixj = t ^ j;
                if (ixj > t) {
                    unsigned long long a = keys[t], c = keys[ixj];
                    bool sw = ((t & k) == 0) ? (a < c) : (a > c);
                    if (sw) { keys[t] = c; keys[ixj] = a; }
                }
            }
            __syncthreads();
        }
    }

    // ---- Phase C: stage sorted boxes (swizzled) + alive bitmasks --------
    for (int pass = 0; pass < NBOX / BLK; ++pass) {
        int i = pass * BLK + tid;
        unsigned long long key = keys[i];
        unsigned int idx = ~(unsigned int)key;          // recover original index
        float4 v = bb4[idx];
        sbox[i ^ ((i >> 5) & 7)] = v;
        bool valid = ((unsigned int)(key >> 32)) != 0u;
        unsigned long long bal = __ballot(valid);       // wave covers 64-aligned i range
        if ((tid & 63) == 0) {
            int w = i >> 5;                             // even, 64-aligned base
            aliveW[w]     = (unsigned int)bal;
            aliveW[w + 1] = (unsigned int)(bal >> 32);
        }
    }
    __syncthreads();

    // ---- Phase D: single-wave register-resident greedy NMS --------------
    if (tid >= 64) return;  // no barriers beyond this point
    const int lane = tid;

    // lane owns sorted indices [lane*32, lane*32+32) in registers
    float x1[32], y1[32], x2[32], y2[32], ar[32];
#pragma unroll
    for (int s = 0; s < 32; ++s) {
        float4 v = sbox[lane * 32 + (s ^ (lane & 7))];  // = phys(lane*32+s): conflict-free
        x1[s] = v.x; y1[s] = v.y; x2[s] = v.z; y2[s] = v.w;
        ar[s] = (v.z - v.x) * (v.w - v.y);
    }
    unsigned int alive = aliveW[lane];  // 1 = valid, unprocessed, unsuppressed

    float* regions = out;
    float* maskv   = out + (size_t)NIMG * MAXDET * 5;

    int nkept = 0;
    while (nkept < MAXDET) {
        unsigned long long bal = __ballot(alive != 0u);
        if (bal == 0ULL) break;
        int owner = (int)__builtin_ctzll(bal);          // smallest lane with live bit
        unsigned int aw = (unsigned int)__shfl((int)alive, owner);
        int cand = (owner << 5) + (int)__builtin_ctz(aw);  // global min alive index = leader

        float4 L = sbox[cand ^ ((cand >> 5) & 7)];      // uniform LDS read (broadcast)
        float larea = (L.z - L.x) * (L.w - L.y);

        if (lane == 0) {
            float* r = regions + ((size_t)(b * MAXDET + nkept)) * 5;
            r[0] = (float)b; r[1] = L.x; r[2] = L.y; r[3] = L.z; r[4] = L.w;
            maskv[b * MAXDET + nkept] = 1.0f;
        }
        nkept++;

        // suppress vs leader: pure register sweep; leader clears itself (IoU=1)
        unsigned int kill = 0;
#pragma unroll
        for (int c = 0; c < 4; ++c) {
            if ((alive >> (c * 8)) & 0xFFu) {           // skip fully-dead chunks
#pragma unroll
                for (int s8 = 0; s8 < 8; ++s8) {
                    int s = c * 8 + s8;
                    float iw = fminf(L.z, x2[s]) - fmaxf(L.x, x1[s]);
                    float ih = fminf(L.w, y2[s]) - fmaxf(L.y, y1[s]);
                    iw = fmaxf(iw, 0.0f);
                    ih = fmaxf(ih, 0.0f);
                    float inter = iw * ih;
                    float denom = (larea + ar[s]) - inter;  // ref op order: (a_j + a_i) - inter
                    if ((double)inter > IOU_MID * (double)denom) kill |= (1u << s);
                }
            }
        }
        alive &= ~kill;
    }

    // ---- Phase E: fill padding rows (d_out is poisoned every launch) ----
    for (int k2 = nkept + lane; k2 < MAXDET; k2 += 64) {
        float* r = regions + ((size_t)(b * MAXDET + k2)) * 5;
        r[0] = (float)b; r[1] = 0.0f; r[2] = 0.0f; r[3] = 0.0f; r[4] = 0.0f;
        maskv[b * MAXDET + k2] = 0.0f;
    }
}

extern "C" void kernel_launch(void* const* d_in, const int* in_sizes, int n_in,
                              void* d_out, int out_size, void* d_ws, size_t ws_size,
                              hipStream_t stream) {
    const float* boxes  = (const float*)d_in[0];  // [8,2048,4] f32
    const float* scores = (const float*)d_in[1];  // [8,2048]   f32
    float* out = (float*)d_out;                   // 4800 f32: regions(4000) ++ mask(800)
    region_extractor_kernel<<<NIMG, BLK, 0, stream>>>(boxes, scores, out);
}

// Round 4
// 218.427 us; speedup vs baseline: 1.8682x; 1.0560x over previous
//
#include <hip/hip_runtime.h>

#define NBOX   2048
#define MAXDET 100
#define NIMG   8
#define BLK    512
// midpoint(0.3f, nextafterf(0.3f, +inf)) in double:
// RN_f32(inter/denom) > 0.3f  <=>  inter > IOU_MID * denom  (exact: products fit f64)
#define IOU_MID 0x1.333335p-2

// __launch_bounds__(512, 2): 2 waves/SIMD floor -> 256-VGPR cap, enough for the
// 160-reg per-lane box array in phase D (bare (512) capped at 116 and spilled).
__global__ __launch_bounds__(BLK, 2) void region_extractor_kernel(
    const float* __restrict__ boxes,   // [NIMG, NBOX, 4] xyxy
    const float* __restrict__ scores,  // [NIMG, NBOX]
    float* __restrict__ out)           // [NIMG*MAXDET*5] regions ++ [NIMG*MAXDET] mask
{
    __shared__ unsigned long long keys[NBOX];   // 16 KB
    __shared__ float4 sbox[NBOX];               // 32 KB, XOR-swizzled: phys = i ^ ((i>>5)&7)
    __shared__ unsigned int aliveW[NBOX / 32];  // 64 words: bit (i&31) of word (i>>5) = valid

    const int tid = threadIdx.x;
    const int b   = blockIdx.x;
    const float4* bb4 = (const float4*)(boxes + (size_t)b * NBOX * 4);
    const float*  ss  = scores + (size_t)b * NBOX;

    // ---- Phase A: validity + composite sort key -------------------------
    // key = (score_bits << 32) | ~idx : descending sort == (score desc, idx asc);
    // invalid -> hi = 0 (== -inf: sorts last)
    for (int i = tid; i < NBOX; i += BLK) {
        float4 v = bb4[i];
        float  s = ss[i];
        bool valid = ((v.z - v.x) >= 25.0f) && ((v.w - v.y) >= 25.0f) && (s >= 0.001f);
        unsigned int sk = valid ? __float_as_uint(s) : 0u;  // scores in [0,1): bits monotone
        keys[i] = ((unsigned long long)sk << 32) | (unsigned int)(~i);
    }
    __syncthreads();

    // ---- Phase B: bitonic sort, descending ------------------------------
    for (int k = 2; k <= NBOX; k <<= 1) {
        for (int j = k >> 1; j > 0; j >>= 1) {
            for (int t = tid; t < NBOX; t += BLK) {
                int ixj = t ^ j;
                if (ixj > t) {
                    unsigned long long a = keys[t], c = keys[ixj];
                    bool sw = ((t & k) == 0) ? (a < c) : (a > c);
                    if (sw) { keys[t] = c; keys[ixj] = a; }
                }
            }
            __syncthreads();
        }
    }

    // ---- Phase C: stage sorted boxes (swizzled) + alive bitmasks --------
    for (int pass = 0; pass < NBOX / BLK; ++pass) {
        int i = pass * BLK + tid;
        unsigned long long key = keys[i];
        unsigned int idx = ~(unsigned int)key;          // recover original index
        float4 v = bb4[idx];
        sbox[i ^ ((i >> 5) & 7)] = v;
        bool valid = ((unsigned int)(key >> 32)) != 0u;
        unsigned long long bal = __ballot(valid);       // wave covers 64-aligned i range
        if ((tid & 63) == 0) {
            int w = i >> 5;                             // even, 64-aligned base
            aliveW[w]     = (unsigned int)bal;
            aliveW[w + 1] = (unsigned int)(bal >> 32);
        }
    }
    __syncthreads();

    // ---- Phase D: single-wave register-resident greedy NMS --------------
    if (tid >= 64) return;  // no barriers beyond this point
    const int lane = tid;

    // lane owns sorted indices [lane*32, lane*32+32) in registers (160 VGPRs)
    float x1[32], y1[32], x2[32], y2[32], ar[32];
#pragma unroll
    for (int s = 0; s < 32; ++s) {
        float4 v = sbox[lane * 32 + (s ^ (lane & 7))];  // = phys(lane*32+s): conflict-free
        x1[s] = v.x; y1[s] = v.y; x2[s] = v.z; y2[s] = v.w;
        ar[s] = (v.z - v.x) * (v.w - v.y);
    }
    unsigned int alive = aliveW[lane];  // 1 = valid, unprocessed, unsuppressed

    float* regions = out;
    float* maskv   = out + (size_t)NIMG * MAXDET * 5;

    int nkept = 0;
    while (nkept < MAXDET) {
        unsigned long long bal = __ballot(alive != 0u);
        if (bal == 0ULL) break;
        int owner = (int)__builtin_ctzll(bal);          // smallest lane with live bit
        unsigned int aw = (unsigned int)__shfl((int)alive, owner);
        int cand = (owner << 5) + (int)__builtin_ctz(aw);  // global min alive index = leader

        float4 L = sbox[cand ^ ((cand >> 5) & 7)];      // uniform LDS read (broadcast)
        float larea = (L.z - L.x) * (L.w - L.y);

        if (lane == 0) {
            float* r = regions + ((size_t)(b * MAXDET + nkept)) * 5;
            r[0] = (float)b; r[1] = L.x; r[2] = L.y; r[3] = L.z; r[4] = L.w;
            maskv[b * MAXDET + nkept] = 1.0f;
        }
        nkept++;

        // suppress vs leader: straight-line register sweep (32 independent tests,
        // no divergent chunk branches); leader clears itself (IoU = 1)
        unsigned int kill = 0;
#pragma unroll
        for (int s = 0; s < 32; ++s) {
            float iw = fminf(L.z, x2[s]) - fmaxf(L.x, x1[s]);
            float ih = fminf(L.w, y2[s]) - fmaxf(L.y, y1[s]);
            iw = fmaxf(iw, 0.0f);
            ih = fmaxf(ih, 0.0f);
            float inter = iw * ih;
            float denom = (larea + ar[s]) - inter;      // ref op order: (a_j + a_i) - inter
            if ((double)inter > IOU_MID * (double)denom) kill |= (1u << s);
        }
        alive &= ~kill;
    }

    // ---- Phase E: fill padding rows (d_out is poisoned every launch) ----
    for (int k2 = nkept + lane; k2 < MAXDET; k2 += 64) {
        float* r = regions + ((size_t)(b * MAXDET + k2)) * 5;
        r[0] = (float)b; r[1] = 0.0f; r[2] = 0.0f; r[3] = 0.0f; r[4] = 0.0f;
        maskv[b * MAXDET + k2] = 0.0f;
    }
}

extern "C" void kernel_launch(void* const* d_in, const int* in_sizes, int n_in,
                              void* d_out, int out_size, void* d_ws, size_t ws_size,
                              hipStream_t stream) {
    const float* boxes  = (const float*)d_in[0];  // [8,2048,4] f32
    const float* scores = (const float*)d_in[1];  // [8,2048]   f32
    float* out = (float*)d_out;                   // 4800 f32: regions(4000) ++ mask(800)
    region_extractor_kernel<<<NIMG, BLK, 0, stream>>>(boxes, scores, out);
}

// Round 5
// 131.205 us; speedup vs baseline: 3.1101x; 1.6648x over previous
//
#include <hip/hip_runtime.h>

#define NBOX   2048
#define MAXDET 100
#define NIMG   8
#define BLK    512
#define NWAVE  (BLK / 64)   // 8 waves
#define INFI   0x7FFFFFFF
// midpoint(0.3f, nextafterf(0.3f,+inf)) in double:
// RN_f32(inter/denom) > 0.3f  <=>  inter > IOU_MID * denom  (25b x 24b product exact in f64)
#define IOU_MID 0x1.333335p-2

#define FOR4(OP) OP(0) OP(1) OP(2) OP(3)

__global__ __launch_bounds__(BLK) void region_extractor_kernel(
    const float* __restrict__ boxes,   // [NIMG, NBOX, 4] xyxy
    const float* __restrict__ scores,  // [NIMG, NBOX]
    float* __restrict__ out)           // [NIMG*MAXDET*5] regions ++ [NIMG*MAXDET] mask
{
    __shared__ unsigned long long keys[NBOX];  // 16 KB
    __shared__ int   candW[NWAVE];             // per-wave leader candidates
    __shared__ float lbox[4];                  // broadcast leader box

    const int g    = threadIdx.x;              // 0..511
    const int wave = g >> 6;
    const int lane = g & 63;
    const int b    = blockIdx.x;
    const float4* bb4 = (const float4*)(boxes + (size_t)b * NBOX * 4);
    const float*  ss  = scores + (size_t)b * NBOX;

    // ---- Phase A: validity + composite sort key -------------------------
    // key = (score_bits << 32) | ~idx : descending sort == (score desc, idx asc);
    // invalid -> hi = 0 (== -inf: sorts last). scores in [0,1): bits monotone.
    for (int p = 0; p < NBOX / BLK; ++p) {
        int i = p * BLK + g;
        float4 v = bb4[i];
        float  s = ss[i];
        bool valid = ((v.z - v.x) >= 25.0f) && ((v.w - v.y) >= 25.0f) && (s >= 0.001f);
        unsigned int sk = valid ? __float_as_uint(s) : 0u;
        keys[i] = ((unsigned long long)sk << 32) | (unsigned int)(~i);
    }
    __syncthreads();

    // ---- Phase B: bitonic sort, descending. 1024 pairs/step, 2/thread,
    // each pair touched exactly once (no masked-off iterations).
    for (int k = 2; k <= NBOX; k <<= 1) {
        for (int j = k >> 1; j > 0; j >>= 1) {
#pragma unroll
            for (int h = 0; h < 2; ++h) {
                int t = h * BLK + g;                       // 0..1023
                int i = ((t & ~(j - 1)) << 1) | (t & (j - 1));
                int q = i | j;                             // partner (bit j set)
                unsigned long long a = keys[i], c = keys[q];
                bool swp = ((i & k) == 0) ? (a < c) : (a > c);
                if (swp) { keys[i] = c; keys[q] = a; }
            }
            __syncthreads();
        }
    }

    // ---- Phase C: lane g owns sorted indices [4g, 4g+4) in NAMED registers
    // (scalars, not arrays -> guaranteed mem2reg, no scratch spill)
#define DECLB(i) float x1_##i, y1_##i, x2_##i, y2_##i, ar_##i;
    FOR4(DECLB)
    unsigned int alive = 0;  // bit i: box 4g+i valid & unsuppressed & unprocessed
#define LOADB(i) { unsigned long long key = keys[4 * g + i];                 \
        unsigned int idx = ~(unsigned int)key;                               \
        float4 v = bb4[idx];                                                 \
        x1_##i = v.x; y1_##i = v.y; x2_##i = v.z; y2_##i = v.w;              \
        ar_##i = (v.z - v.x) * (v.w - v.y);                                  \
        if ((unsigned int)(key >> 32) != 0u) alive |= (1u << i); }
    FOR4(LOADB)

    float* regions = out;
    float* maskv   = out + (size_t)NIMG * MAXDET * 5;
    int nkept = 0;

    // ---- Phase D: 8-wave greedy NMS, 2 barriers/iteration ---------------
    for (;;) {
        // per-wave min alive sorted index (lane-major layout => ballot+ctz)
        int cand = INFI;
        unsigned long long bal = __ballot(alive != 0u);
        if (bal != 0ULL) {
            int owner = (int)__builtin_ctzll(bal);
            unsigned int aw = (unsigned int)__shfl((int)alive, owner);
            cand = (((wave << 6) + owner) << 2) + (int)__builtin_ctz(aw);
        }
        if (lane == 0) candW[wave] = cand;
        __syncthreads();

        int lead = candW[0];
#pragma unroll
        for (int w = 1; w < NWAVE; ++w) lead = min(lead, candW[w]);
        if (lead == INFI) break;                 // uniform: no alive boxes left

        if (g == (lead >> 2)) {                  // owning lane posts leader box
            int k2 = lead & 3;
            float sx = x1_0, sy = y1_0, sz = x2_0, sww = y2_0;
            if (k2 == 1) { sx = x1_1; sy = y1_1; sz = x2_1; sww = y2_1; }
            if (k2 == 2) { sx = x1_2; sy = y1_2; sz = x2_2; sww = y2_2; }
            if (k2 == 3) { sx = x1_3; sy = y1_3; sz = x2_3; sww = y2_3; }
            lbox[0] = sx; lbox[1] = sy; lbox[2] = sz; lbox[3] = sww;
        }
        __syncthreads();

        float Lx = lbox[0], Ly = lbox[1], Lz = lbox[2], Lw = lbox[3];
        float larea = (Lz - Lx) * (Lw - Ly);

        if (g == 0) {                            // emit kept row (fire-and-forget)
            float* r = regions + ((size_t)(b * MAXDET + nkept)) * 5;
            r[0] = (float)b; r[1] = Lx; r[2] = Ly; r[3] = Lz; r[4] = Lw;
            maskv[b * MAXDET + nkept] = 1.0f;
        }
        nkept++;
        if (nkept >= MAXDET) break;

        // suppression sweep: 4 register IoU tests/lane; leader self-kills (IoU=1)
        unsigned int kill = 0;
#define TESTB(i) {                                                           \
        float iw = fminf(Lz, x2_##i) - fmaxf(Lx, x1_##i);                    \
        float ih = fminf(Lw, y2_##i) - fmaxf(Ly, y1_##i);                    \
        iw = fmaxf(iw, 0.0f); ih = fmaxf(ih, 0.0f);                          \
        float inter = iw * ih;                                               \
        float denom = (larea + ar_##i) - inter; /* ref: (a_j + a_i) - inter */ \
        if ((double)inter > IOU_MID * (double)denom) kill |= (1u << i); }
        FOR4(TESTB)
        alive &= ~kill;
    }

    // ---- Phase E: fill padding rows (d_out is poisoned every launch) ----
    for (int r = nkept + g; r < MAXDET; r += BLK) {
        float* rr = regions + ((size_t)(b * MAXDET + r)) * 5;
        rr[0] = (float)b; rr[1] = 0.0f; rr[2] = 0.0f; rr[3] = 0.0f; rr[4] = 0.0f;
        maskv[b * MAXDET + r] = 0.0f;
    }
}

extern "C" void kernel_launch(void* const* d_in, const int* in_sizes, int n_in,
                              void* d_out, int out_size, void* d_ws, size_t ws_size,
                              hipStream_t stream) {
    const float* boxes  = (const float*)d_in[0];  // [8,2048,4] f32
    const float* scores = (const float*)d_in[1];  // [8,2048]   f32
    float* out = (float*)d_out;                   // 4800 f32: regions(4000) ++ mask(800)
    region_extractor_kernel<<<NIMG, BLK, 0, stream>>>(boxes, scores, out);
}

// Round 6
// 121.695 us; speedup vs baseline: 3.3531x; 1.0781x over previous
//
#include <hip/hip_runtime.h>

#define NBOX   2048
#define MAXDET 100
#define NIMG   8
#define BLK    512
#define NWAVE  (BLK / 64)   // 8 waves
#define INFI   0x7FFFFFFF
// midpoint(0.3f, nextafterf(0.3f,+inf)) in double:
// RN_f32(inter/denom) > 0.3f  <=>  inter > IOU_MID * denom
// (25-bit mid x 24-bit denom product is exact in f64; tie==mid rounds to even=0.3f -> "false" matches)
#define IOU_MID 0x1.333335p-2

#define FOR4(OP) OP(0) OP(1) OP(2) OP(3)

// Bank-conflict-free padded LDS indexing:
//  keys (u64): bank pair = (2*phys)%32, determined by phys%16 -> pad 1 per 16
//  sbox (float4): bank quad = (4*phys)%32, determined by phys%8 -> pad 1 per 8
__device__ __forceinline__ int KP(int i) { return i + (i >> 4); }
__device__ __forceinline__ int SP(int i) { return i + (i >> 3); }
#define KEYSZ  (NBOX + NBOX / 16)   // 2176 u64  = 17408 B
#define SBOXSZ (NBOX + NBOX / 8)    // 2304 f4   = 36864 B

#define CMPX(a, b) { if (d ? ((a) < (b)) : ((a) > (b))) { unsigned long long _t = (a); (a) = (b); (b) = _t; } }

__global__ __launch_bounds__(BLK) void region_extractor_kernel(
    const float* __restrict__ boxes,   // [NIMG, NBOX, 4] xyxy
    const float* __restrict__ scores,  // [NIMG, NBOX]
    float* __restrict__ out)           // [NIMG*MAXDET*5] regions ++ [NIMG*MAXDET] mask
{
    __shared__ unsigned long long keys[KEYSZ];
    __shared__ float4 sbox[SBOXSZ];
    __shared__ int candW[2][NWAVE];    // parity-double-buffered leader candidates

    const int g    = threadIdx.x;      // 0..511
    const int wave = g >> 6;
    const int lane = g & 63;
    const int b    = blockIdx.x;
    const float4* bb4 = (const float4*)(boxes + (size_t)b * NBOX * 4);
    const float*  ss  = scores + (size_t)b * NBOX;

    // ---- Phase A: validity + composite sort key -------------------------
    // key = (score_bits << 32) | ~idx : descending sort == (score desc, idx asc);
    // invalid -> hi = 0 (== -inf: sorts last). scores in [0,1): bits monotone.
    for (int p = 0; p < NBOX / BLK; ++p) {
        int i = p * BLK + g;
        float4 v = bb4[i];
        float  s = ss[i];
        bool valid = ((v.z - v.x) >= 25.0f) && ((v.w - v.y) >= 25.0f) && (s >= 0.001f);
        unsigned int sk = valid ? __float_as_uint(s) : 0u;
        keys[KP(i)] = ((unsigned long long)sk << 32) | (unsigned int)(~i);
    }
    __syncthreads();

    // ---- Phase B: bitonic sort, descending ------------------------------
    // Thread g owns aligned 4-block [4g, 4g+4) for register-fused j<=2 stages
    // (KP is contiguous inside any aligned 16-block, so base+0..3 is valid).
    {   // fused k=2 (j=1) + k=4 (j=2, j=1)
        int base = KP(4 * g);
        unsigned long long w0 = keys[base], w1 = keys[base + 1],
                           w2 = keys[base + 2], w3 = keys[base + 3];
        { bool d = true;  CMPX(w0, w1) }          // k=2: pair(0,1) desc ((4g)&2==0)
        { bool d = false; CMPX(w2, w3) }          // k=2: pair(2,3) asc
        { bool d = ((g & 1) == 0);                // k=4: dir uniform over block
          CMPX(w0, w2) CMPX(w1, w3) CMPX(w0, w1) CMPX(w2, w3) }
        keys[base] = w0; keys[base + 1] = w1; keys[base + 2] = w2; keys[base + 3] = w3;
    }
    __syncthreads();

    for (int k = 8; k <= NBOX; k <<= 1) {
        for (int j = k >> 1; j >= 4; j >>= 1) {   // LDS stages
#pragma unroll
            for (int h = 0; h < 2; ++h) {
                int t = h * BLK + g;                       // 0..1023 pair ids
                int i = ((t & ~(j - 1)) << 1) | (t & (j - 1));
                int q = i | j;
                unsigned long long a = keys[KP(i)], c = keys[KP(q)];
                bool swp = ((i & k) == 0) ? (a < c) : (a > c);
                if (swp) { keys[KP(i)] = c; keys[KP(q)] = a; }
            }
            __syncthreads();
        }
        {   // fused j=2, j=1 register pass (dir uniform: (4g)&k, k>=8)
            int base = KP(4 * g);
            unsigned long long w0 = keys[base], w1 = keys[base + 1],
                               w2 = keys[base + 2], w3 = keys[base + 3];
            bool d = (((4 * g) & k) == 0);
            CMPX(w0, w2) CMPX(w1, w3) CMPX(w0, w1) CMPX(w2, w3)
            keys[base] = w0; keys[base + 1] = w1; keys[base + 2] = w2; keys[base + 3] = w3;
        }
        __syncthreads();
    }

    // ---- Phase C: lane g owns sorted indices [4g,4g+4) in NAMED registers
    // (scalars -> mem2reg, no scratch); also stage sorted boxes to sbox for
    // the uniform leader-broadcast read in phase D.
#define DECLB(i) float x1_##i, y1_##i, x2_##i, y2_##i, ar_##i;
    FOR4(DECLB)
    unsigned int alive = 0;  // bit i: box 4g+i valid & unsuppressed & unprocessed
#define LOADB(i) { unsigned long long key = keys[KP(4 * g) + i];             \
        unsigned int idx = ~(unsigned int)key;                               \
        float4 v = bb4[idx];                                                 \
        x1_##i = v.x; y1_##i = v.y; x2_##i = v.z; y2_##i = v.w;              \
        ar_##i = (v.z - v.x) * (v.w - v.y);                                  \
        sbox[SP(4 * g + i)] = v;                                             \
        if ((unsigned int)(key >> 32) != 0u) alive |= (1u << i); }
    FOR4(LOADB)
    __syncthreads();

    float* regions = out;
    float* maskv   = out + (size_t)NIMG * MAXDET * 5;
    int nkept = 0;

    // ---- Phase D: 8-wave greedy NMS, ONE barrier/iteration --------------
    for (int it = 0; ; ++it) {
        // per-wave min alive sorted index (lane-major layout => ballot+ctz)
        int cand = INFI;
        unsigned long long bal = __ballot(alive != 0u);
        if (bal != 0ULL) {
            int owner = (int)__builtin_ctzll(bal);
            unsigned int aw = (unsigned int)__shfl((int)alive, owner);
            cand = (((wave << 6) + owner) << 2) + (int)__builtin_ctz(aw);
        }
        if (lane == 0) candW[it & 1][wave] = cand;
        __syncthreads();   // parity buffer => post(it+1) can't race readers of (it)

        const int* cw = candW[it & 1];
        int lead = min(min(min(cw[0], cw[1]), min(cw[2], cw[3])),
                       min(min(cw[4], cw[5]), min(cw[6], cw[7])));
        if (lead == INFI) break;                 // uniform: nothing alive

        float4 L = sbox[SP(lead)];               // uniform LDS read -> broadcast
        float larea = (L.z - L.x) * (L.w - L.y);

        if (g == 0) {                            // emit kept row
            float* r = regions + ((size_t)(b * MAXDET + nkept)) * 5;
            r[0] = (float)b; r[1] = L.x; r[2] = L.y; r[3] = L.z; r[4] = L.w;
            maskv[b * MAXDET + nkept] = 1.0f;
        }
        nkept++;
        if (nkept >= MAXDET) break;              // uniform

        // suppression sweep: 4 register IoU tests/lane; leader self-kills (IoU=1)
        unsigned int kill = 0;
#define TESTB(i) {                                                           \
        float iw = fminf(L.z, x2_##i) - fmaxf(L.x, x1_##i);                  \
        float ih = fminf(L.w, y2_##i) - fmaxf(L.y, y1_##i);                  \
        iw = fmaxf(iw, 0.0f); ih = fmaxf(ih, 0.0f);                          \
        float inter = iw * ih;                                               \
        float denom = (larea + ar_##i) - inter; /* ref: (a_j + a_i) - inter */ \
        if ((double)inter > IOU_MID * (double)denom) kill |= (1u << i); }
        FOR4(TESTB)
        alive &= ~kill;
    }

    // ---- Phase E: fill padding rows (d_out is poisoned every launch) ----
    for (int r = nkept + g; r < MAXDET; r += BLK) {
        float* rr = regions + ((size_t)(b * MAXDET + r)) * 5;
        rr[0] = (float)b; rr[1] = 0.0f; rr[2] = 0.0f; rr[3] = 0.0f; rr[4] = 0.0f;
        maskv[b * MAXDET + r] = 0.0f;
    }
}

extern "C" void kernel_launch(void* const* d_in, const int* in_sizes, int n_in,
                              void* d_out, int out_size, void* d_ws, size_t ws_size,
                              hipStream_t stream) {
    const float* boxes  = (const float*)d_in[0];  // [8,2048,4] f32
    const float* scores = (const float*)d_in[1];  // [8,2048]   f32
    float* out = (float*)d_out;                   // 4800 f32: regions(4000) ++ mask(800)
    region_extractor_kernel<<<NIMG, BLK, 0, stream>>>(boxes, scores, out);
}